// Round 10
// baseline (564.987 us; speedup 1.0000x reference)
//
#include <hip/hip_runtime.h>
#include <stdint.h>

typedef float  f32x4  __attribute__((ext_vector_type(4)));
typedef short  short8 __attribute__((ext_vector_type(8)));
typedef __bf16 bf16x8 __attribute__((ext_vector_type(8)));

__device__ __forceinline__ unsigned short f2bf(float f) {
    unsigned u = __builtin_bit_cast(unsigned, f);
    unsigned r = u + 0x7fffu + ((u >> 16) & 1u);   // round-to-nearest-even
    return (unsigned short)(r >> 16);
}

__device__ __forceinline__ short8 cvt8(f32x4 a, f32x4 b) {
    short8 r;
    r[0] = (short)f2bf(a[0]); r[1] = (short)f2bf(a[1]);
    r[2] = (short)f2bf(a[2]); r[3] = (short)f2bf(a[3]);
    r[4] = (short)f2bf(b[0]); r[5] = (short)f2bf(b[1]);
    r[6] = (short)f2bf(b[2]); r[7] = (short)f2bf(b[3]);
    return r;
}

typedef const __attribute__((address_space(1))) void* gas_p;
typedef __attribute__((address_space(3))) void*       las_p;
__device__ __forceinline__ void gld_lds16(const void* g, void* l) {
    __builtin_amdgcn_global_load_lds((gas_p)g, (las_p)l, 16, 0, 0);
}

__device__ __forceinline__ f32x4 mfma16(short8 a, short8 b, f32x4 c) {
    return __builtin_amdgcn_mfma_f32_16x16x32_bf16(
        __builtin_bit_cast(bf16x8, a), __builtin_bit_cast(bf16x8, b), c, 0, 0, 0);
}

// ---------------------------------------------------------------------------
// Small GEMM:  St[n][m] = sum_k X[m][k] * W[k][n]   (K = 128 fixed)
// (unchanged — validated, ~2% of runtime)
// ---------------------------------------------------------------------------
template<int NMAT>
__global__ __launch_bounds__(256) void k_xw_t(const float* __restrict__ X,
                                              const float* __restrict__ W,
                                              short* __restrict__ St, int M) {
    constexpr int K   = 128;
    constexpr int NPT = NMAT / 4;
    __shared__ float Xs[64][129];
    __shared__ float Ws[K][NMAT];

    const int tid = threadIdx.x;
    const int m0  = blockIdx.x * 64;

    constexpr int WCH = K * NMAT / 4 / 256;
    #pragma unroll
    for (int j = 0; j < WCH; ++j) {
        int ch = tid + j * 256;
        ((float4*)Ws)[ch] = ((const float4*)W)[ch];
    }
    #pragma unroll
    for (int j = 0; j < 8; ++j) {
        int ch = tid + j * 256;
        int r = ch >> 5, c4 = ch & 31;
        float4 v = *(const float4*)(X + (size_t)(m0 + r) * K + c4 * 4);
        Xs[r][c4 * 4 + 0] = v.x; Xs[r][c4 * 4 + 1] = v.y;
        Xs[r][c4 * 4 + 2] = v.z; Xs[r][c4 * 4 + 3] = v.w;
    }
    __syncthreads();

    const int m  = tid & 63;
    const int n0 = (tid >> 6) * NPT;
    float acc[NPT];
    #pragma unroll
    for (int i = 0; i < NPT; ++i) acc[i] = 0.f;

    for (int k = 0; k < K; ++k) {
        float x = Xs[m][k];
        #pragma unroll
        for (int i = 0; i < NPT; i += 4) {
            float4 w = *(const float4*)&Ws[k][n0 + i];
            acc[i + 0] += x * w.x; acc[i + 1] += x * w.y;
            acc[i + 2] += x * w.z; acc[i + 3] += x * w.w;
        }
    }
    #pragma unroll
    for (int i = 0; i < NPT; ++i)
        St[(size_t)(n0 + i) * M + m0 + m] = (short)f2bf(acc[i]);
}

// ---------------------------------------------------------------------------
// Streaming GEMM:  out[m][n] = sum_k adj[m][k] * S[k][n]  (+bias, opt. relu)
//  v10 = v9 + per-block K-phase stagger (r9 post-mortem: r4/r8/r9 all plateau
//  at ~4.3 TB/s regardless of schedule -> suspect channel-phase aliasing:
//  row stride 64 KB makes all BM requests of an iteration hit the same HBM
//  channel phase (kt mod C), and all blocks started at kt=0 in lockstep).
//  Block b starts at physical tile kt0=(b*97)&255 and wraps; each tile still
//  processed exactly once (fp32 accumulation order change is ~1e-7 rel).
//  Everything else identical to v9:
//  - BM=64, 256 thr, 4 waves = 4M x 1N, wave-exclusive A rows, A global->reg
//    2 tiles deep, cvt in reg, zero duplicated loads.
//  - B: global_load_lds DMA, triple-buffered, ONE barrier/iter.
//  - vmcnt(BCH+4) keeps {B(t+1),A(t+2)} in flight across the barrier.
//  - XOR swizzle (row&7)<<4 on B (pre-swizzled DMA source, linear dest).
// ---------------------------------------------------------------------------
template<int BN, bool RELU>
__global__ __launch_bounds__(256, 2) void k_adj_gemm(const float* __restrict__ A,
                                                     const short* __restrict__ Bt,
                                                     const float* __restrict__ bias,
                                                     float* __restrict__ out,
                                                     int M, int K) {
    constexpr int BM    = 64, BK = 64;
    constexpr int NF    = BN / 16;                    // n-frags (full width): 8 or 4
    constexpr int BCH   = BN * BK * 2 / (256 * 16);   // B-DMA per thread: 4 or 2
    constexpr int VMCNT = BCH + 4;                    // keep {B(t+1), A(t+2)}

    __shared__ short Bs[3][BN * 64];                  // 3 x 16/8 KB

    const int tid  = threadIdx.x;
    const int wave = tid >> 6, lane = tid & 63;
    const int lr   = lane & 15, lk = lane >> 4;
    const int row0 = blockIdx.x * BM;
    const int row_g = row0 + wave * 16 + lr;          // wave-exclusive rows

    const char* Abase = (const char*)A + (size_t)row_g * K * 4 + lk * 32;

    const int key   = (lr & 7) << 4;                  // XOR swizzle key
    const int offs0 = (lk * 16) ^ key;                // B k-half 0
    const int offs1 = (64 + lk * 16) ^ key;           // B k-half 1

    f32x4 acc[NF];
    #pragma unroll
    for (int n = 0; n < NF; ++n) acc[n] = (f32x4)0.f;

    f32x4 a0[4], a1[4];                               // A slots, 2 tiles deep
    const int NT  = K / BK;                           // 256 (power of 2)
    const int NTM = NT - 1;
    const int kt0 = (blockIdx.x * 97) & NTM;          // per-block K phase

#define LOAD_A(SLOT, KTP)                                                       \
    {                                                                           \
        const char* p = Abase + (size_t)(KTP) * 256;                            \
        SLOT[0] = *(const f32x4*)(p);                                           \
        SLOT[1] = *(const f32x4*)(p + 16);                                      \
        SLOT[2] = *(const f32x4*)(p + 128);                                     \
        SLOT[3] = *(const f32x4*)(p + 144);                                     \
    }
#define STAGE_B(BUF, KTP)                                                       \
    {                                                                           \
        _Pragma("unroll")                                                       \
        for (int j = 0; j < BCH; ++j) {                                         \
            int o = (tid + j * 256) * 16;        /* linear byte off, B tile */  \
            int r = o >> 7, w = o & 127;                                        \
            const char* src = (const char*)Bt + (size_t)r * (K * 2)             \
                              + (size_t)(KTP) * 128 + (w ^ ((r & 7) << 4));     \
            gld_lds16(src, (char*)&Bs[BUF][0] + o);                             \
        }                                                                       \
    }

    // prologue at this block's phase (issue order: A,A,B -> steady-state vmcnt)
    LOAD_A(a0, kt0)
    LOAD_A(a1, (kt0 + 1) & NTM)
    STAGE_B(0, kt0)

#define ITER(KT, SA, CB, NB)                                                    \
    {                                                                           \
        /* cvt A(t) -> bf16 frags (compiler auto-waits exactly on SA regs) */   \
        short8 fa0 = cvt8(SA[0], SA[1]);                                        \
        short8 fa1 = cvt8(SA[2], SA[3]);                                        \
        /* refill A(t+2), stage B(t+1) — physical = (logical+kt0) & NTM     */  \
        { int kta = ((KT) + 2 + kt0) & NTM; LOAD_A(SA, kta) }                   \
        { int ktn = ((KT) + 1 + kt0) & NTM; STAGE_B(NB, ktn) }                  \
        __builtin_amdgcn_sched_barrier(0);                                      \
        /* {B(t),A(t+1)} retired; {B(t+1),A(t+2)} stay in flight */             \
        asm volatile("s_waitcnt vmcnt(%0)" :: "i"(VMCNT) : "memory");           \
        __builtin_amdgcn_s_barrier();            /* the ONLY barrier */         \
        __builtin_amdgcn_sched_barrier(0);                                      \
        /* MFMA over full width, both K-halves */                               \
        _Pragma("unroll")                                                       \
        for (int n = 0; n < NF; ++n) {                                          \
            short8 b0 = *(const short8*)((const char*)&Bs[CB][0]                \
                                         + n * 2048 + lr * 128 + offs0);        \
            acc[n] = mfma16(fa0, b0, acc[n]);                                   \
            short8 b1 = *(const short8*)((const char*)&Bs[CB][0]                \
                                         + n * 2048 + lr * 128 + offs1);        \
            acc[n] = mfma16(fa1, b1, acc[n]);                                   \
        }                                                                       \
    }

    // period-6 rotation (A slot %2, B buf %3): 42*6 = 252 iters + 4 tail
    for (int g = 0; g < 42; ++g) {
        int t = g * 6;
        ITER(t + 0, a0, 0, 1)
        ITER(t + 1, a1, 1, 2)
        ITER(t + 2, a0, 2, 0)
        ITER(t + 3, a1, 0, 1)
        ITER(t + 4, a0, 1, 2)
        ITER(t + 5, a1, 2, 0)
    }
    ITER(252, a0, 0, 1)
    ITER(253, a1, 1, 2)
    ITER(254, a0, 2, 0)
    ITER(255, a1, 0, 1)
#undef ITER
#undef LOAD_A
#undef STAGE_B

    // epilogue: D layout col = lane&15, row = (lane>>4)*4 + j  [m89-verified]
    #pragma unroll
    for (int n = 0; n < NF; ++n) {
        int col = n * 16 + lr;
        float bv = bias[col];
        #pragma unroll
        for (int j = 0; j < 4; ++j) {
            int row = row0 + wave * 16 + lk * 4 + j;
            float v = acc[n][j] + bv;
            if (RELU) v = fmaxf(v, 0.f);
            out[(size_t)row * BN + col] = v;
        }
    }
}

extern "C" void kernel_launch(void* const* d_in, const int* in_sizes, int n_in,
                              void* d_out, int out_size, void* d_ws, size_t ws_size,
                              hipStream_t stream) {
    const int N = 16384, NH1 = 128, NH2 = 64;
    const float* feature = (const float*)d_in[0];
    const float* adj     = (const float*)d_in[1];
    const float* W1      = (const float*)d_in[2];
    const float* b1      = (const float*)d_in[3];
    const float* W2      = (const float*)d_in[4];
    const float* b2      = (const float*)d_in[5];

    short* S1t = (short*)d_ws;                            // [128][16384] bf16, 4 MiB
    float* h   = (float*)((char*)d_ws + (4u << 20));      // [16384][128] fp32, 8 MiB
    short* S2t = (short*)((char*)d_ws + (12u << 20));     // [64][16384]  bf16, 2 MiB

    k_xw_t<NH1><<<N / 64, 256, 0, stream>>>(feature, W1, S1t, N);
    k_adj_gemm<NH1, true ><<<N / 64, 256, 0, stream>>>(adj, S1t, b1, h, N, N);
    k_xw_t<NH2><<<N / 64, 256, 0, stream>>>(h, W2, S2t, N);
    k_adj_gemm<NH2, false><<<N / 64, 256, 0, stream>>>(adj, S2t, b2, (float*)d_out, N, N);
    (void)in_sizes; (void)n_in; (void)out_size; (void)ws_size;
}

// Round 11
// 486.821 us; speedup vs baseline: 1.1606x; 1.1606x over previous
//
#include <hip/hip_runtime.h>
#include <stdint.h>

typedef float  f32x4  __attribute__((ext_vector_type(4)));
typedef short  short8 __attribute__((ext_vector_type(8)));
typedef __bf16 bf16x8 __attribute__((ext_vector_type(8)));

__device__ __forceinline__ unsigned short f2bf(float f) {
    unsigned u = __builtin_bit_cast(unsigned, f);
    unsigned r = u + 0x7fffu + ((u >> 16) & 1u);   // round-to-nearest-even
    return (unsigned short)(r >> 16);
}

__device__ __forceinline__ short8 cvt8(f32x4 a, f32x4 b) {
    short8 r;
    r[0] = (short)f2bf(a[0]); r[1] = (short)f2bf(a[1]);
    r[2] = (short)f2bf(a[2]); r[3] = (short)f2bf(a[3]);
    r[4] = (short)f2bf(b[0]); r[5] = (short)f2bf(b[1]);
    r[6] = (short)f2bf(b[2]); r[7] = (short)f2bf(b[3]);
    return r;
}

typedef const __attribute__((address_space(1))) void* gas_p;
typedef __attribute__((address_space(3))) void*       las_p;
__device__ __forceinline__ void gld_lds16(const void* g, void* l) {
    __builtin_amdgcn_global_load_lds((gas_p)g, (las_p)l, 16, 0, 0);
}

__device__ __forceinline__ f32x4 mfma16(short8 a, short8 b, f32x4 c) {
    return __builtin_amdgcn_mfma_f32_16x16x32_bf16(
        __builtin_bit_cast(bf16x8, a), __builtin_bit_cast(bf16x8, b), c, 0, 0, 0);
}

// ---------------------------------------------------------------------------
// Small GEMM:  St[n][m] = sum_k X[m][k] * W[k][n]   (K = 128 fixed)
// (unchanged — validated, ~2% of runtime)
// ---------------------------------------------------------------------------
template<int NMAT>
__global__ __launch_bounds__(256) void k_xw_t(const float* __restrict__ X,
                                              const float* __restrict__ W,
                                              short* __restrict__ St, int M) {
    constexpr int K   = 128;
    constexpr int NPT = NMAT / 4;
    __shared__ float Xs[64][129];
    __shared__ float Ws[K][NMAT];

    const int tid = threadIdx.x;
    const int m0  = blockIdx.x * 64;

    constexpr int WCH = K * NMAT / 4 / 256;
    #pragma unroll
    for (int j = 0; j < WCH; ++j) {
        int ch = tid + j * 256;
        ((float4*)Ws)[ch] = ((const float4*)W)[ch];
    }
    #pragma unroll
    for (int j = 0; j < 8; ++j) {
        int ch = tid + j * 256;
        int r = ch >> 5, c4 = ch & 31;
        float4 v = *(const float4*)(X + (size_t)(m0 + r) * K + c4 * 4);
        Xs[r][c4 * 4 + 0] = v.x; Xs[r][c4 * 4 + 1] = v.y;
        Xs[r][c4 * 4 + 2] = v.z; Xs[r][c4 * 4 + 3] = v.w;
    }
    __syncthreads();

    const int m  = tid & 63;
    const int n0 = (tid >> 6) * NPT;
    float acc[NPT];
    #pragma unroll
    for (int i = 0; i < NPT; ++i) acc[i] = 0.f;

    for (int k = 0; k < K; ++k) {
        float x = Xs[m][k];
        #pragma unroll
        for (int i = 0; i < NPT; i += 4) {
            float4 w = *(const float4*)&Ws[k][n0 + i];
            acc[i + 0] += x * w.x; acc[i + 1] += x * w.y;
            acc[i + 2] += x * w.z; acc[i + 3] += x * w.w;
        }
    }
    #pragma unroll
    for (int i = 0; i < NPT; ++i)
        St[(size_t)(n0 + i) * M + m0 + m] = (short)f2bf(acc[i]);
}

// ---------------------------------------------------------------------------
// Streaming GEMM:  out[m][n] = sum_k adj[m][k] * S[k][n]  (+bias, opt. relu)
//  v11 = v9 (no stagger — r10 regressed) + BATCH-4 A prefetch:
//  r10 post-mortem points at DRAM page efficiency: 256 B per row-visit at
//  64 KB row stride, revisits ~2400 cyc apart -> pages never hot (~67% eff,
//  matches 4.2/6.3). Fix: every 4th iter a wave issues 16 back-to-back
//  dwordx4 covering 4 K-tiles = 1 KB CONTIGUOUS per row in one burst.
//  - Two 16-slot register batches (128 VGPR, all indices literal),
//    __launch_bounds__(256,1) -> allocator has 512, no spill (r2 lesson).
//  - B: global_load_lds DMA, QUAD-buffered (period 4; lcm with A period 8
//    = 8 -> clean 32x8 unroll). ONE barrier/iter (WAR: buf staged at t was
//    last read at t-3, 4 barriers ago).
//  - Phase-counted vmcnt (issue-order-derived): BCH+16 at phases {0,3},
//    BCH at {1,2}; always forces {A(t),B(t)} retired, keeps the newest
//    batch/B-stage in flight across barriers.
//  - XOR swizzle (row&7)<<4 on B (pre-swizzled DMA source, linear dest).
//  FP accumulation order identical to v9 -> absmax unchanged.
// ---------------------------------------------------------------------------
template<int BN, bool RELU>
__global__ __launch_bounds__(256, 1) void k_adj_gemm(const float* __restrict__ A,
                                                     const short* __restrict__ Bt,
                                                     const float* __restrict__ bias,
                                                     float* __restrict__ out,
                                                     int M, int K) {
    constexpr int BM   = 64, BK = 64;
    constexpr int NF   = BN / 16;                    // n-frags (full width): 8 or 4
    constexpr int BCH  = BN * BK * 2 / (256 * 16);   // B-DMA per thread: 4 or 2
    constexpr int VMH  = BCH + 16;                   // phases 0,3
    constexpr int VML  = BCH;                        // phases 1,2

    __shared__ short Bs[4][BN * 64];                 // 4 x 16/8 KB

    const int tid  = threadIdx.x;
    const int wave = tid >> 6, lane = tid & 63;
    const int lr   = lane & 15, lk = lane >> 4;
    const int row0 = blockIdx.x * BM;
    const int row_g = row0 + wave * 16 + lr;         // wave-exclusive rows

    const char* Abase = (const char*)A + (size_t)row_g * K * 4 + lk * 32;

    const int key   = (lr & 7) << 4;                 // XOR swizzle key
    const int offs0 = (lk * 16) ^ key;               // B k-half 0
    const int offs1 = (64 + lk * 16) ^ key;          // B k-half 1

    f32x4 acc[NF];
    #pragma unroll
    for (int n = 0; n < NF; ++n) acc[n] = (f32x4)0.f;

    f32x4 bA0[16], bA1[16];                          // two 4-tile A batches
    const int NT  = K / BK;                          // 256
    const int NTM = NT - 1;

#define LOAD_SLOT(QARR, BI, TT)                                                 \
    {                                                                           \
        const char* p = Abase + (size_t)(TT) * 256;                             \
        QARR[(BI) + 0] = *(const f32x4*)(p);                                    \
        QARR[(BI) + 1] = *(const f32x4*)(p + 16);                               \
        QARR[(BI) + 2] = *(const f32x4*)(p + 128);                              \
        QARR[(BI) + 3] = *(const f32x4*)(p + 144);                              \
    }
#define LOAD_BATCH(QARR, T0)                                                    \
    {                                                                           \
        LOAD_SLOT(QARR, 0,  ((T0) + 0) & NTM)                                   \
        LOAD_SLOT(QARR, 4,  ((T0) + 1) & NTM)                                   \
        LOAD_SLOT(QARR, 8,  ((T0) + 2) & NTM)                                   \
        LOAD_SLOT(QARR, 12, ((T0) + 3) & NTM)                                   \
    }
#define STAGE_B(BUF, KTP)                                                       \
    {                                                                           \
        _Pragma("unroll")                                                       \
        for (int j = 0; j < BCH; ++j) {                                         \
            int o = (tid + j * 256) * 16;        /* linear byte off, B tile */  \
            int r = o >> 7, w = o & 127;                                        \
            const char* src = (const char*)Bt + (size_t)r * (K * 2)             \
                              + (size_t)(KTP) * 128 + (w ^ ((r & 7) << 4));     \
            gld_lds16(src, (char*)&Bs[BUF][0] + o);                             \
        }                                                                       \
    }

    // prologue: batch0 (tiles 0-3), B(0), batch1 (tiles 4-7).
    // -> ops newer than B(0) at iter 0: batch1(16) + B(1)(BCH) = VMH. Exact.
    LOAD_BATCH(bA0, 0)
    STAGE_B(0, 0)
    LOAD_BATCH(bA1, 4)

#define ITER(KT, QARR, J4, CB, NB, VM, BATCH_STMT)                              \
    {                                                                           \
        /* cvt A(t) (compiler waits exactly on these 4 slots) */                \
        short8 fa0 = cvt8(QARR[(J4) + 0], QARR[(J4) + 1]);                      \
        short8 fa1 = cvt8(QARR[(J4) + 2], QARR[(J4) + 3]);                      \
        { int ktn = ((KT) + 1) & NTM; STAGE_B(NB, ktn) }                        \
        BATCH_STMT                                                              \
        __builtin_amdgcn_sched_barrier(0);                                      \
        /* force {A(t),B(t)} retired; newest batch/B-stage stay in flight */    \
        asm volatile("s_waitcnt vmcnt(%0)" :: "i"(VM) : "memory");              \
        __builtin_amdgcn_s_barrier();            /* the ONLY barrier */         \
        __builtin_amdgcn_sched_barrier(0);                                      \
        _Pragma("unroll")                                                       \
        for (int n = 0; n < NF; ++n) {                                          \
            short8 b0 = *(const short8*)((const char*)&Bs[CB][0]                \
                                         + n * 2048 + lr * 128 + offs0);        \
            acc[n] = mfma16(fa0, b0, acc[n]);                                   \
            short8 b1 = *(const short8*)((const char*)&Bs[CB][0]                \
                                         + n * 2048 + lr * 128 + offs1);        \
            acc[n] = mfma16(fa1, b1, acc[n]);                                   \
        }                                                                       \
    }

    // period-8 schedule: A batch q=(t>>2)&1 phase t&3; B buf t&3. 256 = 32*8.
    for (int g = 0; g < 32; ++g) {
        int t = g * 8;
        ITER(t + 0, bA0, 0,  0, 1, VMH, )
        ITER(t + 1, bA0, 4,  1, 2, VML, )
        ITER(t + 2, bA0, 8,  2, 3, VML, )
        ITER(t + 3, bA0, 12, 3, 0, VMH, LOAD_BATCH(bA0, (t + 3) + 5))
        ITER(t + 4, bA1, 0,  0, 1, VMH, )
        ITER(t + 5, bA1, 4,  1, 2, VML, )
        ITER(t + 6, bA1, 8,  2, 3, VML, )
        ITER(t + 7, bA1, 12, 3, 0, VMH, LOAD_BATCH(bA1, (t + 7) + 5))
    }
#undef ITER
#undef LOAD_BATCH
#undef LOAD_SLOT
#undef STAGE_B

    // epilogue: D layout col = lane&15, row = (lane>>4)*4 + j  [m89-verified]
    #pragma unroll
    for (int n = 0; n < NF; ++n) {
        int col = n * 16 + lr;
        float bv = bias[col];
        #pragma unroll
        for (int j = 0; j < 4; ++j) {
            int row = row0 + wave * 16 + lk * 4 + j;
            float v = acc[n][j] + bv;
            if (RELU) v = fmaxf(v, 0.f);
            out[(size_t)row * BN + col] = v;
        }
    }
}

extern "C" void kernel_launch(void* const* d_in, const int* in_sizes, int n_in,
                              void* d_out, int out_size, void* d_ws, size_t ws_size,
                              hipStream_t stream) {
    const int N = 16384, NH1 = 128, NH2 = 64;
    const float* feature = (const float*)d_in[0];
    const float* adj     = (const float*)d_in[1];
    const float* W1      = (const float*)d_in[2];
    const float* b1      = (const float*)d_in[3];
    const float* W2      = (const float*)d_in[4];
    const float* b2      = (const float*)d_in[5];

    short* S1t = (short*)d_ws;                            // [128][16384] bf16, 4 MiB
    float* h   = (float*)((char*)d_ws + (4u << 20));      // [16384][128] fp32, 8 MiB
    short* S2t = (short*)((char*)d_ws + (12u << 20));     // [64][16384]  bf16, 2 MiB

    k_xw_t<NH1><<<N / 64, 256, 0, stream>>>(feature, W1, S1t, N);
    k_adj_gemm<NH1, true ><<<N / 64, 256, 0, stream>>>(adj, S1t, b1, h, N, N);
    k_xw_t<NH2><<<N / 64, 256, 0, stream>>>(h, W2, S2t, N);
    k_adj_gemm<NH2, false><<<N / 64, 256, 0, stream>>>(adj, S2t, b2, (float*)d_out, N, N);
    (void)in_sizes; (void)n_in; (void)out_size; (void)ws_size;
}